// Round 7
// baseline (347.480 us; speedup 1.0000x reference)
//
#include <hip/hip_runtime.h>
#include <hip/hip_bf16.h>
#include <stdint.h>

typedef __attribute__((ext_vector_type(8))) short bf16x8;
typedef __attribute__((ext_vector_type(4))) float f32x4;
typedef __attribute__((ext_vector_type(16))) float f32x16;

#define AS1(p) ((const __attribute__((address_space(1))) void*)(p))
#define AS3(p) ((__attribute__((address_space(3))) void*)(p))

static __device__ __forceinline__ unsigned short f2bf(float f) {
  union { float f; unsigned u; } v; v.f = f;
  unsigned r = v.u + 0x7fffu + ((v.u >> 16) & 1u);   // RNE
  return (unsigned short)(r >> 16);
}
static __device__ __forceinline__ float f4get(float4 v, int r) {
  return r == 0 ? v.x : r == 1 ? v.y : r == 2 ? v.z : v.w;
}
static __device__ __forceinline__ int grow(int rowbase, int t) {
  return rowbase + (t / 7) * 56 + (t % 7);
}

// ------------------------------------------- cast + transpose weights -> [N][K] bf16
// SCALE = 32^-0.5 folded into the Q columns (n < 256) of w_qkv.
__global__ __launch_bounds__(256) void prep_w_kernel(const float* __restrict__ wqkv,
                                                     const float* __restrict__ wout,
                                                     unsigned short* __restrict__ wqkvT,
                                                     unsigned short* __restrict__ woutT) {
  int id = blockIdx.x * 256 + threadIdx.x;
  if (id < 768 * 256) {
    int n = id >> 8, k = id & 255;
    float v = wqkv[k * 768 + n];
    if (n < 256) v *= 0.17677669529663687f;
    wqkvT[id] = f2bf(v);
  } else {
    int id2 = id - 768 * 256;
    int n = id2 >> 8, k = id2 & 255;
    woutT[id2] = f2bf(wout[k * 256 + n]);
  }
}

// ---------------------------------------------------------------- bf16 MFMA GEMM
// A: [M x 256] row-major; CAST_A ? f32 (fused cast via reg-staging) : bf16 (global_load_lds).
// Bt: [N x 256] bf16 (k contiguous).  Tile 128x128, BK=64, 4 waves (2x2),
// wave = 64x64 = 4x4 frags of 16x16x32.  LDS 16B chunks XOR-swizzled.
// 1-D grid, m-major/n-minor + bijective XCD swizzle (gridDim.x % 8 == 0).
template <int N_COLS, bool CAST_A, bool OUT_F32, bool BIAS>
__global__ __launch_bounds__(256) void gemm_kernel(const void* __restrict__ Ain,
                                                   const unsigned short* __restrict__ Bt,
                                                   void* __restrict__ Cout,
                                                   const float* __restrict__ bias) {
  constexpr int K = 256;
  constexpr int NB = N_COLS / 128;
  __shared__ __align__(16) unsigned short lA[128 * 64];
  __shared__ __align__(16) unsigned short lB[128 * 64];
  const int tid = threadIdx.x;
  const int lane = tid & 63;
  const int wid = tid >> 6;
  const int wr = wid >> 1, wc = wid & 1;

  const int orig = blockIdx.x;
  const int cpx = gridDim.x >> 3;
  const int swz = (orig & 7) * cpx + (orig >> 3);
  const int m0 = (swz / NB) * 128;
  const int n0 = (swz % NB) * 128;

  f32x4 acc[4][4];
#pragma unroll
  for (int i = 0; i < 4; ++i)
#pragma unroll
    for (int j = 0; j < 4; ++j) acc[i][j] = (f32x4){0.f, 0.f, 0.f, 0.f};

  for (int k0 = 0; k0 < K; k0 += 64) {
    if (CAST_A) {
      // fused-cast A staging: f32 global -> regs -> bf16 -> swizzled LDS chunk
      const float* Af = (const float*)Ain;
      float4 u[4][2];
#pragma unroll
      for (int i = 0; i < 4; ++i) {                  // issue all loads first
        int cidx = i * 256 + tid;
        int r = cidx >> 3, cc = cidx & 7;
        int scc = cc ^ (r & 7);
        const float* g = Af + (size_t)(m0 + r) * K + k0 + scc * 8;
        u[i][0] = ((const float4*)g)[0];
        u[i][1] = ((const float4*)g)[1];
      }
#pragma unroll
      for (int i = 0; i < 4; ++i) {                  // convert + ds_write_b128
        int cidx = i * 256 + tid;
        union { unsigned short s[8]; bf16x8 v; } pk;
        pk.s[0] = f2bf(u[i][0].x); pk.s[1] = f2bf(u[i][0].y);
        pk.s[2] = f2bf(u[i][0].z); pk.s[3] = f2bf(u[i][0].w);
        pk.s[4] = f2bf(u[i][1].x); pk.s[5] = f2bf(u[i][1].y);
        pk.s[6] = f2bf(u[i][1].z); pk.s[7] = f2bf(u[i][1].w);
        *reinterpret_cast<bf16x8*>(&lA[cidx * 8]) = pk.v;
      }
    } else {
      const unsigned short* Ab = (const unsigned short*)Ain;
#pragma unroll
      for (int i = 0; i < 4; ++i) {
        int cidx = i * 256 + tid;
        int r = cidx >> 3, cc = cidx & 7;
        int scc = cc ^ (r & 7);
        const unsigned short* g = Ab + (size_t)(m0 + r) * K + k0 + scc * 8;
        __builtin_amdgcn_global_load_lds(AS1(g), AS3(&lA[cidx * 8]), 16, 0, 0);
      }
    }
#pragma unroll
    for (int i = 0; i < 4; ++i) {
      int cidx = i * 256 + tid;
      int r = cidx >> 3, cc = cidx & 7;
      int scc = cc ^ (r & 7);
      const unsigned short* g = Bt + (size_t)(n0 + r) * K + k0 + scc * 8;
      __builtin_amdgcn_global_load_lds(AS1(g), AS3(&lB[cidx * 8]), 16, 0, 0);
    }
    __syncthreads();
#pragma unroll
    for (int kk = 0; kk < 2; ++kk) {
      bf16x8 af[4], bfr[4];
#pragma unroll
      for (int mi = 0; mi < 4; ++mi) {
        int r = wr * 64 + mi * 16 + (lane & 15);
        int kc = kk * 4 + (lane >> 4);
        int pc = kc ^ (r & 7);
        af[mi] = *reinterpret_cast<const bf16x8*>(&lA[r * 64 + pc * 8]);
      }
#pragma unroll
      for (int ni = 0; ni < 4; ++ni) {
        int r = wc * 64 + ni * 16 + (lane & 15);
        int kc = kk * 4 + (lane >> 4);
        int pc = kc ^ (r & 7);
        bfr[ni] = *reinterpret_cast<const bf16x8*>(&lB[r * 64 + pc * 8]);
      }
#pragma unroll
      for (int mi = 0; mi < 4; ++mi)
#pragma unroll
        for (int ni = 0; ni < 4; ++ni)
          acc[mi][ni] = __builtin_amdgcn_mfma_f32_16x16x32_bf16(af[mi], bfr[ni],
                                                                acc[mi][ni], 0, 0, 0);
    }
    __syncthreads();
  }

  const int rif = (lane >> 4) * 4;
  const int cif = lane & 15;
#pragma unroll
  for (int mi = 0; mi < 4; ++mi) {
#pragma unroll
    for (int ni = 0; ni < 4; ++ni) {
      int col = n0 + wc * 64 + ni * 16 + cif;
      float bv = BIAS ? bias[col] : 0.f;
#pragma unroll
      for (int j = 0; j < 4; ++j) {
        int row = m0 + wr * 64 + mi * 16 + rif + j;
        float v = acc[mi][ni][j] + bv;
        if (OUT_F32)
          ((float*)Cout)[(size_t)row * N_COLS + col] = v;
        else
          ((unsigned short*)Cout)[(size_t)row * N_COLS + col] = f2bf(v);
      }
    }
  }
}

// ---------------------------------------------------------------- MFMA window attention
// One block per WINDOW, 8 waves = all 8 heads: each window's qkv rows are fetched
// once (L1/L2-shared across the 8 head-waves) and the bias table is built once.
// Per wave: 32x32x16 MFMA, swapped QK^T, in-register softmax, cvt_pk +
// permlane32_swap for P->A-frag, V transposed into per-wave LDS for PV B-frags.
__global__ __launch_bounds__(512) void attn_mfma_kernel(const unsigned short* __restrict__ qkv,
                                                        const float* __restrict__ pe,
                                                        unsigned short* __restrict__ aout) {
  __shared__ float biasL[64 * 64];                 // chunk-swizzled: (i, j) -> [i*64 + ((j>>2)^(i&15))*4 + (j&3)]
  __shared__ unsigned short Vt[8][32 * 72];        // per-wave V^T [d][j], stride 72
  const int tid = threadIdx.x;

  for (int id = tid; id < 4096; id += 512) {
    int i = id >> 6, j = id & 63;
    float v = 0.f;
    if (i < 49 && j < 49) {
      int xi = i / 7, yi = i % 7, xj = j / 7, yj = j % 7;
      v = pe[(xj - xi + 6) * 13 + (yj - yi + 6)];
    }
    biasL[i * 64 + ((((unsigned)j >> 2) ^ (i & 15)) << 2) + (j & 3)] = v;
  }
  __syncthreads();

  const int lane = tid & 63;
  const int wv = tid >> 6;                         // wave = head
  const int hi = lane >> 5;
  const int l31 = lane & 31;
  const int h = wv;
  const int win = blockIdx.x;
  const int rowbase = (win >> 6) * 3136 + ((win & 63) >> 3) * 392 + (win & 7) * 7;
  unsigned short* vt = Vt[wv];

  // ---- V row load (column j = lane of V^T), zero the pad columns
  const int vrow = lane < 49 ? lane : 48;
  const unsigned short* vpr = qkv + (size_t)grow(rowbase, vrow) * 768 + h * 32 + 512;
  bf16x8 vr[4];
#pragma unroll
  for (int t = 0; t < 4; ++t) vr[t] = *(const bf16x8*)(vpr + t * 8);
  if (lane >= 49) {
#pragma unroll
    for (int t = 0; t < 4; ++t) vr[t] = bf16x8{0, 0, 0, 0, 0, 0, 0, 0};
  }

  // ---- Q/K fragments straight from global (head_dim contiguous)
  bf16x8 qf[2][2], kf[2][2];
#pragma unroll
  for (int t = 0; t < 2; ++t) {
    int r = t * 32 + l31; if (r > 48) r = 48;
    const unsigned short* base = qkv + (size_t)grow(rowbase, r) * 768 + h * 32;
#pragma unroll
    for (int ks = 0; ks < 2; ++ks) {
      qf[t][ks] = *(const bf16x8*)(base + ks * 16 + hi * 8);
      kf[t][ks] = *(const bf16x8*)(base + 256 + ks * 16 + hi * 8);
    }
  }

  // ---- QK^T swapped: acc[mi][ni] = S^T tile, D[j][i], col=lane&31 = i
  f32x16 acc[2][2];
#pragma unroll
  for (int mi = 0; mi < 2; ++mi)
#pragma unroll
    for (int ni = 0; ni < 2; ++ni) {
#pragma unroll
      for (int z = 0; z < 16; ++z) acc[mi][ni][z] = 0.f;
#pragma unroll
      for (int ks = 0; ks < 2; ++ks)
        acc[mi][ni] = __builtin_amdgcn_mfma_f32_32x32x16_bf16(kf[mi][ks], qf[ni][ks],
                                                              acc[mi][ni], 0, 0, 0);
    }

  // ---- V transpose into LDS (hidden under MFMA latency)
#pragma unroll
  for (int t = 0; t < 4; ++t)
#pragma unroll
    for (int e = 0; e < 8; ++e)
      vt[(t * 8 + e) * 72 + lane] = (unsigned short)vr[t][e];

  // ---- softmax, fully in-register; pack P to bf16 pairs
  unsigned int pkw[2][2][4][2];                    // [ni][mi][q][w]
#pragma unroll
  for (int ni = 0; ni < 2; ++ni) {
    const int i = ni * 32 + l31;
    float s[32];
    float m = -3e38f;
#pragma unroll
    for (int mi = 0; mi < 2; ++mi)
#pragma unroll
      for (int q = 0; q < 4; ++q) {
        int cc = (mi * 8 + q * 2 + hi) ^ (i & 15);
        float4 b4 = *(const float4*)&biasL[i * 64 + cc * 4];
#pragma unroll
        for (int r = 0; r < 4; ++r) {
          float v = acc[mi][ni][q * 4 + r] + f4get(b4, r);
          s[mi * 16 + q * 4 + r] = v;
          int j0 = mi * 32 + q * 8 + r;            // j = j0 + 4*hi
          if (j0 + 4 * hi < 49) m = fmaxf(m, v);
        }
      }
    m = fmaxf(m, __shfl_xor(m, 32, 64));
    float sum = 0.f;
#pragma unroll
    for (int mi = 0; mi < 2; ++mi)
#pragma unroll
      for (int q = 0; q < 4; ++q)
#pragma unroll
        for (int r = 0; r < 4; ++r) {
          int j0 = mi * 32 + q * 8 + r;
          int idx = mi * 16 + q * 4 + r;
          float e = (j0 + 4 * hi < 49) ? __expf(s[idx] - m) : 0.f;
          s[idx] = e;
          sum += e;
        }
    sum += __shfl_xor(sum, 32, 64);
    float inv = 1.f / sum;
#pragma unroll
    for (int mi = 0; mi < 2; ++mi)
#pragma unroll
      for (int q = 0; q < 4; ++q)
#pragma unroll
        for (int w = 0; w < 2; ++w) {
          float lo = s[mi * 16 + q * 4 + 2 * w] * inv;
          float hp = s[mi * 16 + q * 4 + 2 * w + 1] * inv;
          unsigned int d;
          asm("v_cvt_pk_bf16_f32 %0, %1, %2" : "=v"(d) : "v"(lo), "v"(hp));
          pkw[ni][mi][q][w] = d;
        }
  }

  // ---- PV: out[oi] (64x32), A = P frags via permlane32_swap, B = V^T from LDS
  bf16x8 vfr[4];
#pragma unroll
  for (int ks = 0; ks < 4; ++ks)
    vfr[ks] = *(const bf16x8*)&vt[l31 * 72 + ks * 16 + hi * 8];

  f32x16 oacc[2];
#pragma unroll
  for (int oi = 0; oi < 2; ++oi) {
#pragma unroll
    for (int z = 0; z < 16; ++z) oacc[oi][z] = 0.f;
#pragma unroll
    for (int ks = 0; ks < 4; ++ks) {
      unsigned int a0 = pkw[oi][ks >> 1][(ks & 1) * 2][0];
      unsigned int a1 = pkw[oi][ks >> 1][(ks & 1) * 2][1];
      unsigned int b0 = pkw[oi][ks >> 1][(ks & 1) * 2 + 1][0];
      unsigned int b1 = pkw[oi][ks >> 1][(ks & 1) * 2 + 1][1];
      asm("v_permlane32_swap_b32 %0, %1" : "+v"(a0), "+v"(b0));
      asm("v_permlane32_swap_b32 %0, %1" : "+v"(a1), "+v"(b1));
      union { unsigned int u[4]; bf16x8 v; } pf;
      pf.u[0] = a0; pf.u[1] = a1; pf.u[2] = b0; pf.u[3] = b1;
      oacc[oi] = __builtin_amdgcn_mfma_f32_32x32x16_bf16(pf.v, vfr[ks], oacc[oi], 0, 0, 0);
    }
  }

  // ---- store: D col=lane&31 = d, row = (reg&3)+8*(reg>>2)+4*hi
#pragma unroll
  for (int oi = 0; oi < 2; ++oi)
#pragma unroll
    for (int reg = 0; reg < 16; ++reg) {
      int i = oi * 32 + (reg & 3) + 8 * (reg >> 2) + 4 * hi;
      if (i < 49)
        aout[(size_t)grow(rowbase, i) * 256 + h * 32 + l31] = f2bf(oacc[oi][reg]);
    }
}

// ---------------------------------------------------------------- launcher
extern "C" void kernel_launch(void* const* d_in, const int* in_sizes, int n_in,
                              void* d_out, int out_size, void* d_ws, size_t ws_size,
                              hipStream_t stream) {
  const float* x       = (const float*)d_in[0];
  const float* w_qkv   = (const float*)d_in[1];
  const float* w_out   = (const float*)d_in[2];
  const float* b_out   = (const float*)d_in[3];
  const float* pos_emb = (const float*)d_in[4];
  float* out = (float*)d_out;

  const int M = 32 * 56 * 56;                     // 100352
  char* ws = (char*)d_ws;
  unsigned short* qkv   = (unsigned short*)ws;                          // 154,140,672 B
  unsigned short* aout  = (unsigned short*)(ws + 154140672);            // 51,380,224 B
  unsigned short* wqkvT = (unsigned short*)(ws + 205520896);            // 393,216 B
  unsigned short* woutT = (unsigned short*)(ws + 205914112);            // 131,072 B

  prep_w_kernel<<<dim3(1024), dim3(256), 0, stream>>>(w_qkv, w_out, wqkvT, woutT);
  gemm_kernel<768, true, false, false><<<dim3((M / 128) * 6), dim3(256), 0, stream>>>(x, wqkvT, qkv, nullptr);
  attn_mfma_kernel<<<dim3(2048), dim3(512), 0, stream>>>(qkv, pos_emb, aout);
  gemm_kernel<256, false, true, true><<<dim3((M / 128) * 2), dim3(256), 0, stream>>>(aout, woutT, out, b_out);
}

// Round 8
// 319.861 us; speedup vs baseline: 1.0863x; 1.0863x over previous
//
#include <hip/hip_runtime.h>
#include <hip/hip_bf16.h>
#include <stdint.h>

typedef __attribute__((ext_vector_type(8))) short bf16x8;
typedef __attribute__((ext_vector_type(4))) float f32x4;
typedef __attribute__((ext_vector_type(16))) float f32x16;

#define AS1(p) ((const __attribute__((address_space(1))) void*)(p))
#define AS3(p) ((__attribute__((address_space(3))) void*)(p))

static __device__ __forceinline__ unsigned short f2bf(float f) {
  union { float f; unsigned u; } v; v.f = f;
  unsigned r = v.u + 0x7fffu + ((v.u >> 16) & 1u);   // RNE
  return (unsigned short)(r >> 16);
}
static __device__ __forceinline__ float f4get(float4 v, int r) {
  return r == 0 ? v.x : r == 1 ? v.y : r == 2 ? v.z : v.w;
}
static __device__ __forceinline__ int grow(int rowbase, int t) {
  return rowbase + (t / 7) * 56 + (t % 7);
}

// ---------------------------------------------------------------- cast x -> bf16
__global__ __launch_bounds__(256) void cast_x_kernel(const float* __restrict__ x,
                                                     unsigned short* __restrict__ xb,
                                                     int n4) {
  int idx = blockIdx.x * 256 + threadIdx.x;
  int stride = gridDim.x * 256;
  for (int i = idx; i < n4; i += stride) {
    float4 v = ((const float4*)x)[i];
    ushort4 o;
    o.x = f2bf(v.x); o.y = f2bf(v.y); o.z = f2bf(v.z); o.w = f2bf(v.w);
    ((ushort4*)xb)[i] = o;
  }
}

// ------------------------------------------- cast + transpose weights -> [N][K] bf16
// SCALE = 32^-0.5 folded into the Q columns (n < 256) of w_qkv.
__global__ __launch_bounds__(256) void prep_w_kernel(const float* __restrict__ wqkv,
                                                     const float* __restrict__ wout,
                                                     unsigned short* __restrict__ wqkvT,
                                                     unsigned short* __restrict__ woutT) {
  int id = blockIdx.x * 256 + threadIdx.x;
  if (id < 768 * 256) {
    int n = id >> 8, k = id & 255;
    float v = wqkv[k * 768 + n];
    if (n < 256) v *= 0.17677669529663687f;
    wqkvT[id] = f2bf(v);
  } else {
    int id2 = id - 768 * 256;
    int n = id2 >> 8, k = id2 & 255;
    woutT[id2] = f2bf(wout[k * 256 + n]);
  }
}

// ---------------------------------------------------------------- bf16 MFMA GEMM
// A: [M x 256] bf16 row-major (global_load_lds staging).  Bt: [N x 256] bf16.
// Tile 128x128, BK=64, 4 waves (2x2), wave = 64x64 = 4x4 frags of 16x16x32.
// LDS 16B chunks XOR-swizzled (conflict-free ds_read_b128, measured 0 conflicts).
// 1-D grid, m-major/n-minor + bijective XCD swizzle (gridDim.x % 8 == 0):
// A-panel read ~1x from HBM (measured r6: total -21us vs 2-D grid).
template <int N_COLS, bool OUT_F32, bool BIAS>
__global__ __launch_bounds__(256) void gemm_kernel(const unsigned short* __restrict__ A,
                                                   const unsigned short* __restrict__ Bt,
                                                   void* __restrict__ Cout,
                                                   const float* __restrict__ bias) {
  constexpr int K = 256;
  constexpr int NB = N_COLS / 128;
  __shared__ __align__(16) unsigned short lA[128 * 64];
  __shared__ __align__(16) unsigned short lB[128 * 64];
  const int tid = threadIdx.x;
  const int lane = tid & 63;
  const int wid = tid >> 6;
  const int wr = wid >> 1, wc = wid & 1;

  const int orig = blockIdx.x;
  const int cpx = gridDim.x >> 3;
  const int swz = (orig & 7) * cpx + (orig >> 3);
  const int m0 = (swz / NB) * 128;
  const int n0 = (swz % NB) * 128;

  f32x4 acc[4][4];
#pragma unroll
  for (int i = 0; i < 4; ++i)
#pragma unroll
    for (int j = 0; j < 4; ++j) acc[i][j] = (f32x4){0.f, 0.f, 0.f, 0.f};

  for (int k0 = 0; k0 < K; k0 += 64) {
#pragma unroll
    for (int i = 0; i < 4; ++i) {
      int cidx = i * 256 + tid;
      int r = cidx >> 3, cc = cidx & 7;
      int scc = cc ^ (r & 7);
      const unsigned short* g = A + (size_t)(m0 + r) * K + k0 + scc * 8;
      __builtin_amdgcn_global_load_lds(AS1(g), AS3(&lA[cidx * 8]), 16, 0, 0);
    }
#pragma unroll
    for (int i = 0; i < 4; ++i) {
      int cidx = i * 256 + tid;
      int r = cidx >> 3, cc = cidx & 7;
      int scc = cc ^ (r & 7);
      const unsigned short* g = Bt + (size_t)(n0 + r) * K + k0 + scc * 8;
      __builtin_amdgcn_global_load_lds(AS1(g), AS3(&lB[cidx * 8]), 16, 0, 0);
    }
    __syncthreads();
#pragma unroll
    for (int kk = 0; kk < 2; ++kk) {
      bf16x8 af[4], bfr[4];
#pragma unroll
      for (int mi = 0; mi < 4; ++mi) {
        int r = wr * 64 + mi * 16 + (lane & 15);
        int kc = kk * 4 + (lane >> 4);
        int pc = kc ^ (r & 7);
        af[mi] = *reinterpret_cast<const bf16x8*>(&lA[r * 64 + pc * 8]);
      }
#pragma unroll
      for (int ni = 0; ni < 4; ++ni) {
        int r = wc * 64 + ni * 16 + (lane & 15);
        int kc = kk * 4 + (lane >> 4);
        int pc = kc ^ (r & 7);
        bfr[ni] = *reinterpret_cast<const bf16x8*>(&lB[r * 64 + pc * 8]);
      }
#pragma unroll
      for (int mi = 0; mi < 4; ++mi)
#pragma unroll
        for (int ni = 0; ni < 4; ++ni)
          acc[mi][ni] = __builtin_amdgcn_mfma_f32_16x16x32_bf16(af[mi], bfr[ni],
                                                                acc[mi][ni], 0, 0, 0);
    }
    __syncthreads();
  }

  const int rif = (lane >> 4) * 4;
  const int cif = lane & 15;
#pragma unroll
  for (int mi = 0; mi < 4; ++mi) {
#pragma unroll
    for (int ni = 0; ni < 4; ++ni) {
      int col = n0 + wc * 64 + ni * 16 + cif;
      float bv = BIAS ? bias[col] : 0.f;
#pragma unroll
      for (int j = 0; j < 4; ++j) {
        int row = m0 + wr * 64 + mi * 16 + rif + j;
        float v = acc[mi][ni][j] + bv;
        if (OUT_F32)
          ((float*)Cout)[(size_t)row * N_COLS + col] = v;
        else
          ((unsigned short*)Cout)[(size_t)row * N_COLS + col] = f2bf(v);
      }
    }
  }
}

// ---------------------------------------------------------------- MFMA window attention
// One block per WINDOW, 8 waves = all 8 heads: each window's qkv rows fetched once
// (L1/L2-shared across head-waves), bias table built once (measured r7: ~-20us).
// Per wave: 32x32x16 MFMA, swapped QK^T, in-register softmax, cvt_pk +
// permlane32_swap for P->A-frag, V transposed into per-wave LDS for PV B-frags.
__global__ __launch_bounds__(512) void attn_mfma_kernel(const unsigned short* __restrict__ qkv,
                                                        const float* __restrict__ pe,
                                                        unsigned short* __restrict__ aout) {
  __shared__ float biasL[64 * 64];                 // chunk-swizzled: (i, j) -> [i*64 + ((j>>2)^(i&15))*4 + (j&3)]
  __shared__ unsigned short Vt[8][32 * 72];        // per-wave V^T [d][j], stride 72
  const int tid = threadIdx.x;

  for (int id = tid; id < 4096; id += 512) {
    int i = id >> 6, j = id & 63;
    float v = 0.f;
    if (i < 49 && j < 49) {
      int xi = i / 7, yi = i % 7, xj = j / 7, yj = j % 7;
      v = pe[(xj - xi + 6) * 13 + (yj - yi + 6)];
    }
    biasL[i * 64 + ((((unsigned)j >> 2) ^ (i & 15)) << 2) + (j & 3)] = v;
  }
  __syncthreads();

  const int lane = tid & 63;
  const int wv = tid >> 6;                         // wave = head
  const int hi = lane >> 5;
  const int l31 = lane & 31;
  const int h = wv;
  const int win = blockIdx.x;
  const int rowbase = (win >> 6) * 3136 + ((win & 63) >> 3) * 392 + (win & 7) * 7;
  unsigned short* vt = Vt[wv];

  // ---- V row load (column j = lane of V^T), zero the pad columns
  const int vrow = lane < 49 ? lane : 48;
  const unsigned short* vpr = qkv + (size_t)grow(rowbase, vrow) * 768 + h * 32 + 512;
  bf16x8 vr[4];
#pragma unroll
  for (int t = 0; t < 4; ++t) vr[t] = *(const bf16x8*)(vpr + t * 8);
  if (lane >= 49) {
#pragma unroll
    for (int t = 0; t < 4; ++t) vr[t] = bf16x8{0, 0, 0, 0, 0, 0, 0, 0};
  }

  // ---- Q/K fragments straight from global (head_dim contiguous)
  bf16x8 qf[2][2], kf[2][2];
#pragma unroll
  for (int t = 0; t < 2; ++t) {
    int r = t * 32 + l31; if (r > 48) r = 48;
    const unsigned short* base = qkv + (size_t)grow(rowbase, r) * 768 + h * 32;
#pragma unroll
    for (int ks = 0; ks < 2; ++ks) {
      qf[t][ks] = *(const bf16x8*)(base + ks * 16 + hi * 8);
      kf[t][ks] = *(const bf16x8*)(base + 256 + ks * 16 + hi * 8);
    }
  }

  // ---- QK^T swapped: acc[mi][ni] = S^T tile, D[j][i], col=lane&31 = i
  f32x16 acc[2][2];
#pragma unroll
  for (int mi = 0; mi < 2; ++mi)
#pragma unroll
    for (int ni = 0; ni < 2; ++ni) {
#pragma unroll
      for (int z = 0; z < 16; ++z) acc[mi][ni][z] = 0.f;
#pragma unroll
      for (int ks = 0; ks < 2; ++ks)
        acc[mi][ni] = __builtin_amdgcn_mfma_f32_32x32x16_bf16(kf[mi][ks], qf[ni][ks],
                                                              acc[mi][ni], 0, 0, 0);
    }

  // ---- V transpose into LDS (hidden under MFMA latency)
#pragma unroll
  for (int t = 0; t < 4; ++t)
#pragma unroll
    for (int e = 0; e < 8; ++e)
      vt[(t * 8 + e) * 72 + lane] = (unsigned short)vr[t][e];

  // ---- softmax, fully in-register; pack P to bf16 pairs
  unsigned int pkw[2][2][4][2];                    // [ni][mi][q][w]
#pragma unroll
  for (int ni = 0; ni < 2; ++ni) {
    const int i = ni * 32 + l31;
    float s[32];
    float m = -3e38f;
#pragma unroll
    for (int mi = 0; mi < 2; ++mi)
#pragma unroll
      for (int q = 0; q < 4; ++q) {
        int cc = (mi * 8 + q * 2 + hi) ^ (i & 15);
        float4 b4 = *(const float4*)&biasL[i * 64 + cc * 4];
#pragma unroll
        for (int r = 0; r < 4; ++r) {
          float v = acc[mi][ni][q * 4 + r] + f4get(b4, r);
          s[mi * 16 + q * 4 + r] = v;
          int j0 = mi * 32 + q * 8 + r;            // j = j0 + 4*hi
          if (j0 + 4 * hi < 49) m = fmaxf(m, v);
        }
      }
    m = fmaxf(m, __shfl_xor(m, 32, 64));
    float sum = 0.f;
#pragma unroll
    for (int mi = 0; mi < 2; ++mi)
#pragma unroll
      for (int q = 0; q < 4; ++q)
#pragma unroll
        for (int r = 0; r < 4; ++r) {
          int j0 = mi * 32 + q * 8 + r;
          int idx = mi * 16 + q * 4 + r;
          float e = (j0 + 4 * hi < 49) ? __expf(s[idx] - m) : 0.f;
          s[idx] = e;
          sum += e;
        }
    sum += __shfl_xor(sum, 32, 64);
    float inv = 1.f / sum;
#pragma unroll
    for (int mi = 0; mi < 2; ++mi)
#pragma unroll
      for (int q = 0; q < 4; ++q)
#pragma unroll
        for (int w = 0; w < 2; ++w) {
          float lo = s[mi * 16 + q * 4 + 2 * w] * inv;
          float hp = s[mi * 16 + q * 4 + 2 * w + 1] * inv;
          unsigned int d;
          asm("v_cvt_pk_bf16_f32 %0, %1, %2" : "=v"(d) : "v"(lo), "v"(hp));
          pkw[ni][mi][q][w] = d;
        }
  }

  // ---- PV: out[oi] (64x32), A = P frags via permlane32_swap, B = V^T from LDS
  bf16x8 vfr[4];
#pragma unroll
  for (int ks = 0; ks < 4; ++ks)
    vfr[ks] = *(const bf16x8*)&vt[l31 * 72 + ks * 16 + hi * 8];

  f32x16 oacc[2];
#pragma unroll
  for (int oi = 0; oi < 2; ++oi) {
#pragma unroll
    for (int z = 0; z < 16; ++z) oacc[oi][z] = 0.f;
#pragma unroll
    for (int ks = 0; ks < 4; ++ks) {
      unsigned int a0 = pkw[oi][ks >> 1][(ks & 1) * 2][0];
      unsigned int a1 = pkw[oi][ks >> 1][(ks & 1) * 2][1];
      unsigned int b0 = pkw[oi][ks >> 1][(ks & 1) * 2 + 1][0];
      unsigned int b1 = pkw[oi][ks >> 1][(ks & 1) * 2 + 1][1];
      asm("v_permlane32_swap_b32 %0, %1" : "+v"(a0), "+v"(b0));
      asm("v_permlane32_swap_b32 %0, %1" : "+v"(a1), "+v"(b1));
      union { unsigned int u[4]; bf16x8 v; } pf;
      pf.u[0] = a0; pf.u[1] = a1; pf.u[2] = b0; pf.u[3] = b1;
      oacc[oi] = __builtin_amdgcn_mfma_f32_32x32x16_bf16(pf.v, vfr[ks], oacc[oi], 0, 0, 0);
    }
  }

  // ---- store: D col=lane&31 = d, row = (reg&3)+8*(reg>>2)+4*hi
#pragma unroll
  for (int oi = 0; oi < 2; ++oi)
#pragma unroll
    for (int reg = 0; reg < 16; ++reg) {
      int i = oi * 32 + (reg & 3) + 8 * (reg >> 2) + 4 * hi;
      if (i < 49)
        aout[(size_t)grow(rowbase, i) * 256 + h * 32 + l31] = f2bf(oacc[oi][reg]);
    }
}

// ---------------------------------------------------------------- launcher
extern "C" void kernel_launch(void* const* d_in, const int* in_sizes, int n_in,
                              void* d_out, int out_size, void* d_ws, size_t ws_size,
                              hipStream_t stream) {
  const float* x       = (const float*)d_in[0];
  const float* w_qkv   = (const float*)d_in[1];
  const float* w_out   = (const float*)d_in[2];
  const float* b_out   = (const float*)d_in[3];
  const float* pos_emb = (const float*)d_in[4];
  float* out = (float*)d_out;

  const int M = 32 * 56 * 56;                     // 100352
  char* ws = (char*)d_ws;
  unsigned short* xb    = (unsigned short*)ws;                          // 51,380,224 B
  unsigned short* qkv   = (unsigned short*)(ws + 51380224);             // 154,140,672 B
  unsigned short* aout  = (unsigned short*)(ws + 51380224 + 154140672); // 51,380,224 B
  unsigned short* wqkvT = (unsigned short*)(ws + 256901120);            // 393,216 B
  unsigned short* woutT = (unsigned short*)(ws + 257294336);            // 131,072 B

  cast_x_kernel<<<dim3(2048), dim3(256), 0, stream>>>(x, xb, M * 256 / 4);
  prep_w_kernel<<<dim3(1024), dim3(256), 0, stream>>>(w_qkv, w_out, wqkvT, woutT);
  gemm_kernel<768, false, false><<<dim3((M / 128) * 6), dim3(256), 0, stream>>>(xb, wqkvT, qkv, nullptr);
  attn_mfma_kernel<<<dim3(2048), dim3(512), 0, stream>>>(qkv, pos_emb, aout);
  gemm_kernel<256, true, true><<<dim3((M / 128) * 2), dim3(256), 0, stream>>>(aout, woutT, out, b_out);
}